// Round 11
// baseline (491.986 us; speedup 1.0000x reference)
//
#include <hip/hip_runtime.h>
#include <hip/hip_bf16.h>

// Problem constants
#define V_   16000
#define D_   1024
#define H_   1024
#define E_   8
#define C_   16
#define B_   64
#define S_   512
#define GH_  256
#define NPAIR 128   // B_ * K(=2)

typedef short  bf16x8 __attribute__((ext_vector_type(8)));
typedef ushort u16x8  __attribute__((ext_vector_type(8)));
typedef float  f32x4  __attribute__((ext_vector_type(4)));

static __device__ __forceinline__ ushort f2bf(float f) {
  union { float f; unsigned u; } un; un.f = f;
  unsigned u = un.u;
  return (ushort)((u + 0x7FFFu + ((u >> 16) & 1u)) >> 16);  // RNE
}

static __device__ __forceinline__ unsigned pk2(float lo, float hi) {
  __hip_bfloat162 h = __float22bfloat162_rn(make_float2(lo, hi));  // v_cvt_pk_bf16_f32
  unsigned r; __builtin_memcpy(&r, &h, sizeof(r)); return r;
}

static __device__ __forceinline__ uint4 cvt8(f32x4 a, f32x4 b) {
  uint4 w;
  w.x = pk2(a[0], a[1]); w.y = pk2(a[2], a[3]);
  w.z = pk2(b[0], b[1]); w.w = pk2(b[2], b[3]);
  return w;
}

static __device__ __forceinline__ void gload_lds16(const void* g, void* l) {
  __builtin_amdgcn_global_load_lds((const __attribute__((address_space(1))) void*)g,
                                   (__attribute__((address_space(3))) void*)l, 16, 0, 0);
}

// Tile format (A and B): 16 KB K-tile = [row(128)][64 k] bf16, pre-swizzled in
// global: ushort idx = row*64 + (kcol ^ ((row&7)<<3)). global_load_lds copies
// linearly; ds_read_b128 applies the XOR -> conflict-free (2-way max).

// ---------------------------------------------------------------------------
// Kernel 0 (fused prep):
//  blocks [0,2048): repack exp_w1 (E,D,H) f32 -> w1t tiles [e][mt(8)][kb(16)]
//  blocks [2048,2560): partial pooling partial[b][sb8][d]
__global__ void prep_kernel(const float* __restrict__ w1, ushort* __restrict__ w1t,
                            const int* __restrict__ x, const float* __restrict__ emb,
                            float* __restrict__ partial) {
  __shared__ float tile[64][65];
  const int id = blockIdx.x;
  if (id < 2048) {
    const int e = id >> 8, rem = id & 255;
    const int dtile = rem & 15, htile = rem >> 4;   // dtile = kb, htile = 64-h group
    const int d0 = dtile * 64, h0 = htile * 64;
    const float* src = w1 + (size_t)e * D_ * H_;
    for (int i = threadIdx.x; i < 64 * 64; i += 256) {
      int r = i >> 6, c = i & 63;                 // r: k-local, c: h-local
      tile[r][c] = src[(size_t)(d0 + r) * H_ + h0 + c];
    }
    __syncthreads();
    const int mt = htile >> 1;
    const int rbase = (htile & 1) * 64;
    for (int i = threadIdx.x; i < 512; i += 256) {
      int r64 = i >> 3, kg = i & 7;
      u16x8 v;
      #pragma unroll
      for (int j = 0; j < 8; ++j) v[j] = f2bf(tile[kg * 8 + j][r64]);
      const int r = rbase + r64;
      size_t off = ((size_t)((e * 8 + mt) * 16 + dtile)) * 8192
                   + r * 64 + ((kg * 8) ^ ((r & 7) << 3));
      *reinterpret_cast<u16x8*>(w1t + off) = v;
    }
  } else {
    const int pid = id - 2048;
    const int b = pid >> 3, sb = pid & 7, t = threadIdx.x;
    const int* xr = x + b * S_ + sb * 64;
    float4 acc = make_float4(0.f, 0.f, 0.f, 0.f);
    #pragma unroll 4
    for (int s = 0; s < 64; ++s) {
      const float4* row = reinterpret_cast<const float4*>(emb + (size_t)xr[s] * D_);
      float4 v = row[t];
      acc.x += v.x; acc.y += v.y; acc.z += v.z; acc.w += v.w;
    }
    reinterpret_cast<float4*>(partial + ((size_t)b * 8 + sb) * D_)[t] = acc;
  }
}

// ---------------------------------------------------------------------------
// Kernel 1: reduce partials + gating MLP + top-2 + renormalize (all f32)
__global__ void gate_kernel(const float* __restrict__ partial,
                            const float* __restrict__ gw1, const float* __restrict__ gb1,
                            const float* __restrict__ gw2, const float* __restrict__ gb2,
                            int* __restrict__ ridx, float* __restrict__ rwgt) {
  const int b = blockIdx.x, j = threadIdx.x;
  __shared__ float pl[D_];
  __shared__ float hid[GH_];
  __shared__ float logits[E_];
  for (int d = j; d < D_; d += 256) {
    float s = 0.f;
    #pragma unroll
    for (int sb = 0; sb < 8; ++sb) s += partial[((size_t)b * 8 + sb) * D_ + d];
    pl[d] = s * (1.f / (float)S_);
  }
  __syncthreads();
  float acc = gb1[j];
  for (int d = 0; d < D_; ++d) acc += pl[d] * gw1[d * GH_ + j];
  hid[j] = fmaxf(acc, 0.f);
  __syncthreads();
  if (j < E_) {
    float l = gb2[j];
    for (int i = 0; i < GH_; ++i) l += hid[i] * gw2[i * E_ + j];
    logits[j] = l;
  }
  __syncthreads();
  if (j == 0) {
    int i0 = 0; float v0 = logits[0];
    for (int i = 1; i < E_; ++i) if (logits[i] > v0) { v0 = logits[i]; i0 = i; }
    int i1 = -1; float v1 = -3.0e38f;
    for (int i = 0; i < E_; ++i) {
      if (i == i0) continue;
      if (logits[i] > v1) { v1 = logits[i]; i1 = i; }
    }
    float r1 = expf(v1 - v0);
    float norm = 1.f + r1;
    ridx[b * 2 + 0] = i0;         ridx[b * 2 + 1] = i1;
    rwgt[b * 2 + 0] = 1.f / norm; rwgt[b * 2 + 1] = r1 / norm;
  }
}

// ---------------------------------------------------------------------------
// Kernel 2: stable counting-rank sort of pairs by expert id. 1 block, 128 thr.
__global__ void sort_pairs_kernel(const int* __restrict__ ridx, int* __restrict__ order) {
  __shared__ int se[NPAIR];
  const int t = threadIdx.x;
  se[t] = ridx[t];
  __syncthreads();
  const int e = se[t];
  int rank = 0;
  for (int j = 0; j < NPAIR; ++j) {
    const int ej = se[j];
    rank += (ej < e || (ej == e && j < t)) ? 1 : 0;
  }
  order[rank] = t;
}

// ---------------------------------------------------------------------------
// Kernel 3: gather + f32->bf16 convert of routed tokens into pre-swizzled
//   B tiles xbf[(ss*4+sb4)*16 + kb] (128 tokens x 64 k each).
// grid(1024): block = 64 token rows; 4 blocks/CU for latency hiding.
__global__ __launch_bounds__(256) void gatherconv_kernel(
    const int* __restrict__ x, const float* __restrict__ exp_emb,
    const int* __restrict__ ridx, const int* __restrict__ order,
    ushort* __restrict__ xbf) {
  const int bb = blockIdx.x;            // 0..1023
  const int ss = bb >> 3, h64 = bb & 7;
  const int sb4 = h64 >> 1, r0 = (h64 & 1) * 64;
  const int pr = order[ss], e = ridx[pr], b = pr >> 1;
  const int t = threadIdx.x;
  const int r = r0 + (t >> 2), q4 = t & 3;     // row, quarter of D
  const int tok = x[b * S_ + sb4 * 128 + r];
  const float* src = exp_emb + ((size_t)e * V_ + tok) * D_ + q4 * 256;
  ushort* dstT = xbf + ((size_t)((ss * 4 + sb4) * 16 + q4 * 4)) * 8192 + r * 64;
  const int swz = (r & 7) << 3;
  #pragma unroll
  for (int kb = 0; kb < 4; ++kb) {
    const float* s0 = src + kb * 64;
    f32x4 v[16];
    #pragma unroll
    for (int i = 0; i < 16; ++i)
      v[i] = __builtin_nontemporal_load(reinterpret_cast<const f32x4*>(s0 + i * 4));
    ushort* dst = dstT + (size_t)kb * 8192;
    #pragma unroll
    for (int kg = 0; kg < 8; ++kg) {
      uint4 w = cvt8(v[2 * kg], v[2 * kg + 1]);
      *reinterpret_cast<uint4*>(dst + ((kg * 8) ^ swz)) = w;
    }
  }
}

// ---------------------------------------------------------------------------
// Kernel 4: 256x256-tile phased bf16 GEMM + fused bias/ReLU/s-reduce.
//   Block = (pair, m 0..3, n 0..1): 256 h x 256 s, K = 1024 (16 K-tiles).
//   8 waves (2m x 4n), wave tile 128h x 64s (8x4 16x16 frags, 128 acc VGPR).
//   LDS 128 KiB: 2 K-tile buffers x 4 half-tiles (A0,A1,B0,B1; 16 KB each).
//   Per K-tile: 4 phases {ds_read subtile | stage 1 half-tile (2 gloads) |
//   s_barrier | setprio(1) 16 MFMA setprio(0) | [q3: vmcnt(0)] s_barrier}.
//   vmcnt(0) waits on loads issued 1-4 phases earlier (warm drain, not cold).
//   XCD-chunked bijective swizzle: XCD x owns sorted slots [128x,+128).
// grid(1024), block 512.
__global__ __launch_bounds__(512, 2) void gemm_kernel(
    const ushort* __restrict__ w1t, const ushort* __restrict__ xbf,
    const float* __restrict__ exp_b1,
    const int* __restrict__ ridx, const int* __restrict__ order,
    float* __restrict__ ppart) {
  __shared__ __align__(16) ushort lds[2][4][8192];   // 128 KiB

  const int g    = blockIdx.x;
  const int slot = (g & 7) * 128 + (g >> 3);   // bijective (1024 % 8 == 0)
  const int ss   = slot >> 3;                  // sorted pair slot
  const int sub  = slot & 7;
  const int m    = sub >> 1;                   // h-block (256 h)
  const int n    = sub & 1;                    // s-block (256 s)
  const int pr   = order[ss];
  const int e    = ridx[pr];

  const int tid  = threadIdx.x;
  const int wid  = tid >> 6, lane = tid & 63;
  const int l15  = lane & 15, l16 = lane >> 4;
  const int wm   = wid & 1, wn = wid >> 1;     // 2 x 4 wave grid

  const char* src_u[4] = {
    (const char*)(w1t + ((size_t)((e * 8 + 2 * m    ) * 16)) * 8192),
    (const char*)(w1t + ((size_t)((e * 8 + 2 * m + 1) * 16)) * 8192),
    (const char*)(xbf + ((size_t)((ss * 4 + 2 * n    ) * 16)) * 8192),
    (const char*)(xbf + ((size_t)((ss * 4 + 2 * n + 1) * 16)) * 8192)
  };

  #define STAGE_HT(buf_, u_, kt_) do {                                        \
    const char* s_ = src_u[u_] + (size_t)(kt_) * 16384;                       \
    gload_lds16(s_ + tid * 16,        (char*)&lds[buf_][u_][0] + tid * 16);   \
    gload_lds16(s_ + 8192 + tid * 16, (char*)&lds[buf_][u_][0] + 8192 + tid * 16); \
  } while (0)

  f32x4 acc[8][4];
  #pragma unroll
  for (int f = 0; f < 8; ++f)
    #pragma unroll
    for (int j = 0; j < 4; ++j) acc[f][j] = (f32x4){0.f, 0.f, 0.f, 0.f};

  // prologue: stage K-tile 0 into buf 0
  STAGE_HT(0, 0, 0); STAGE_HT(0, 1, 0); STAGE_HT(0, 2, 0); STAGE_HT(0, 3, 0);
  asm volatile("s_waitcnt vmcnt(0)" ::: "memory");
  __builtin_amdgcn_s_barrier();

  const int browb = (wn & 1) * 64;   // B row base within the wave's B half-tile
  #pragma unroll 2
  for (int kt = 0; kt < 16; ++kt) {
    const int c = kt & 1;
    const ushort* At = &lds[c][wm][0];
    const ushort* Bt = &lds[c][2 + (wn >> 1)][0];
    bf16x8 bfr[4][2];
    #pragma unroll
    for (int q = 0; q < 4; ++q) {
      // ds-load register subtiles (phase q of buf c)
      if (q == 0) {
        #pragma unroll
        for (int j = 0; j < 4; ++j) {
          const int row = browb + j * 16 + l15;
          #pragma unroll
          for (int ks = 0; ks < 2; ++ks)
            bfr[j][ks] = *reinterpret_cast<const bf16x8*>(
                &Bt[row * 64 + ((ks * 32 + l16 * 8) ^ ((row & 7) << 3))]);
        }
      }
      bf16x8 af[2][2];
      #pragma unroll
      for (int fi = 0; fi < 2; ++fi) {
        const int row = (2 * q + fi) * 16 + l15;
        #pragma unroll
        for (int ks = 0; ks < 2; ++ks)
          af[fi][ks] = *reinterpret_cast<const bf16x8*>(
              &At[row * 64 + ((ks * 32 + l16 * 8) ^ ((row & 7) << 3))]);
      }
      // stage half-tile q of K-tile kt+1 into the other buffer
      if (kt < 15) STAGE_HT(c ^ 1, q, kt + 1);
      __builtin_amdgcn_s_barrier();
      __builtin_amdgcn_s_setprio(1);
      #pragma unroll
      for (int fi = 0; fi < 2; ++fi)
        #pragma unroll
        for (int j = 0; j < 4; ++j)
          #pragma unroll
          for (int ks = 0; ks < 2; ++ks)
            acc[2 * q + fi][j] = __builtin_amdgcn_mfma_f32_16x16x32_bf16(
                af[fi][ks], bfr[j][ks], acc[2 * q + fi][j], 0, 0, 0);
      __builtin_amdgcn_s_setprio(0);
      if (q == 3) asm volatile("s_waitcnt vmcnt(0)" ::: "memory");
      __builtin_amdgcn_s_barrier();
    }
  }
  #undef STAGE_HT

  // epilogue: + bias, ReLU, reduce over 256 s (4 j-frags + 16 lanes + 4 wn)
  float* sred = (float*)&lds[0][0][0];   // [wn][wm*128 + hl], 4 KB
  const float* biasE = exp_b1 + e * H_ + m * 256 + wm * 128;
  #pragma unroll
  for (int f = 0; f < 8; ++f) {
    #pragma unroll
    for (int r = 0; r < 4; ++r) {
      const int hl = f * 16 + l16 * 4 + r;    // D row = (lane>>4)*4 + reg
      const float bias = biasE[hl];
      float v = 0.f;
      #pragma unroll
      for (int j = 0; j < 4; ++j) v += fmaxf(acc[f][j][r] + bias, 0.f);
      v += __shfl_xor(v, 1); v += __shfl_xor(v, 2);
      v += __shfl_xor(v, 4); v += __shfl_xor(v, 8);   // reduce 16 s-cols
      if (l15 == 0) sred[wn * 256 + wm * 128 + hl] = v;
    }
  }
  __syncthreads();
  if (tid < 256) {
    const int wmm = tid >> 7, hl = tid & 127;
    const float v = sred[0 * 256 + wmm * 128 + hl] + sred[1 * 256 + wmm * 128 + hl]
                  + sred[2 * 256 + wmm * 128 + hl] + sred[3 * 256 + wmm * 128 + hl];
    ppart[((size_t)n * NPAIR + pr) * H_ + m * 256 + wmm * 128 + hl] = v;
  }
}

// ---------------------------------------------------------------------------
// Kernel 5: out[b][c] = sum_k rw * ( (sum_n ppart)/S @ W2[e] + b2[e] )
__global__ void finalize_kernel(const float* __restrict__ p_part,
                                const int* __restrict__ ridx, const float* __restrict__ rwgt,
                                const float* __restrict__ w2, const float* __restrict__ b2,
                                float* __restrict__ out) {
  const int b = blockIdx.x, t = threadIdx.x;
  const int c = t & 15, g = t >> 4;
  __shared__ float red[16][17];
  float res = 0.f;
  for (int kk = 0; kk < 2; ++kk) {
    const int pr = b * 2 + kk;
    const int e = ridx[pr];
    const float w = rwgt[pr];
    float dot = 0.f;
    for (int h = g; h < H_; h += 16) {
      float pm = p_part[(size_t)(0 * NPAIR + pr) * H_ + h]
               + p_part[(size_t)(1 * NPAIR + pr) * H_ + h];
      dot += pm * w2[((size_t)e * H_ + h) * C_ + c];
    }
    red[g][c] = dot;
    __syncthreads();
    if (g == 0) {
      float s = 0.f;
      #pragma unroll
      for (int i = 0; i < 16; ++i) s += red[i][c];
      res += w * (s * (1.f / (float)S_) + b2[e * C_ + c]);
    }
    __syncthreads();
  }
  if (g == 0) out[b * C_ + c] = res;
}

// ---------------------------------------------------------------------------
extern "C" void kernel_launch(void* const* d_in, const int* in_sizes, int n_in,
                              void* d_out, int out_size, void* d_ws, size_t ws_size,
                              hipStream_t stream) {
  const int*   x    = (const int*)  d_in[0];
  const float* emb  = (const float*)d_in[1];
  const float* gw1  = (const float*)d_in[2];
  const float* gb1  = (const float*)d_in[3];
  const float* gw2  = (const float*)d_in[4];
  const float* gb2  = (const float*)d_in[5];
  const float* eemb = (const float*)d_in[6];
  const float* ew1  = (const float*)d_in[7];
  const float* eb1  = (const float*)d_in[8];
  const float* ew2  = (const float*)d_in[9];
  const float* eb2  = (const float*)d_in[10];
  float* out = (float*)d_out;

  char* ws = (char*)d_ws;
  const size_t OFF_W1T   = 0;                              // 16 MiB
  const size_t OFF_XBF   = (size_t)16 << 20;               // 128 MiB
  const size_t OFF_PART  = (size_t)144 << 20;              // 2 MiB
  const size_t OFF_RIDX  = OFF_PART + ((size_t)2 << 20);
  const size_t OFF_RWGT  = OFF_RIDX + 1024;
  const size_t OFF_ORDER = OFF_RWGT + 1024;
  const size_t OFF_PPART = OFF_ORDER + 1024;               // 1 MiB

  ushort* w1t    = (ushort*)(ws + OFF_W1T);
  ushort* xbf    = (ushort*)(ws + OFF_XBF);
  float*  part   = (float*) (ws + OFF_PART);
  int*    ridx   = (int*)   (ws + OFF_RIDX);
  float*  rwgt   = (float*) (ws + OFF_RWGT);
  int*    order  = (int*)   (ws + OFF_ORDER);
  float*  ppart  = (float*) (ws + OFF_PPART);

  prep_kernel<<<dim3(2560), 256, 0, stream>>>(ew1, w1t, x, emb, part);
  gate_kernel<<<dim3(B_), 256, 0, stream>>>(part, gw1, gb1, gw2, gb2, ridx, rwgt);
  sort_pairs_kernel<<<dim3(1), 128, 0, stream>>>(ridx, order);
  gatherconv_kernel<<<dim3(1024), 256, 0, stream>>>(x, eemb, ridx, order, xbf);
  gemm_kernel<<<dim3(1024), 512, 0, stream>>>(w1t, xbf, eb1, ridx, order, ppart);
  finalize_kernel<<<dim3(B_), 256, 0, stream>>>(ppart, ridx, rwgt, ew2, eb2, out);
}

// Round 12
// 256.901 us; speedup vs baseline: 1.9151x; 1.9151x over previous
//
#include <hip/hip_runtime.h>
#include <hip/hip_bf16.h>

// Problem constants
#define V_   16000
#define D_   1024
#define H_   1024
#define E_   8
#define C_   16
#define B_   64
#define S_   512
#define GH_  256
#define NPAIR 128   // B_ * K(=2)

typedef short  bf16x8 __attribute__((ext_vector_type(8)));
typedef ushort u16x8  __attribute__((ext_vector_type(8)));
typedef float  f32x4  __attribute__((ext_vector_type(4)));

static __device__ __forceinline__ ushort f2bf(float f) {
  union { float f; unsigned u; } un; un.f = f;
  unsigned u = un.u;
  return (ushort)((u + 0x7FFFu + ((u >> 16) & 1u)) >> 16);  // RNE
}

static __device__ __forceinline__ unsigned pk2(float lo, float hi) {
  __hip_bfloat162 h = __float22bfloat162_rn(make_float2(lo, hi));  // v_cvt_pk_bf16_f32
  unsigned r; __builtin_memcpy(&r, &h, sizeof(r)); return r;
}

// ---------------------------------------------------------------------------
// Kernel 0 (fused prep):
//  blocks [0,2048): repack exp_w1 (E,D,H) f32 -> w1t bf16 in MFMA-fragment order:
//   ushort offset = ((e*32 + kk)*64 + f)*512 + lane*8, element j holds
//   A[h = f*16 + (lane&15)][k = kk*32 + (lane>>4)*8 + j]
//  blocks [2048,2560): partial pooling partial[b][sb][d]
__global__ void prep_kernel(const float* __restrict__ w1, ushort* __restrict__ w1t,
                            const int* __restrict__ x, const float* __restrict__ emb,
                            float* __restrict__ partial) {
  __shared__ float tile[64][65];
  const int id = blockIdx.x;
  if (id < 2048) {
    const int e = id >> 8, rem = id & 255;
    const int dtile = rem & 15, htile = rem >> 4;
    const int d0 = dtile * 64, h0 = htile * 64;
    const float* src = w1 + (size_t)e * D_ * H_;
    for (int i = threadIdx.x; i < 64 * 64; i += 256) {
      int r = i >> 6, c = i & 63;                 // r: d-local (k), c: h-local
      tile[r][c] = src[(size_t)(d0 + r) * H_ + h0 + c];
    }
    __syncthreads();
    for (int i = threadIdx.x; i < 512; i += 256) {
      int chunk = i >> 6, lane = i & 63;
      int kkl = chunk >> 2, htl = chunk & 3;
      int l15 = lane & 15, l16 = lane >> 4;
      u16x8 v;
      #pragma unroll
      for (int j = 0; j < 8; ++j)
        v[j] = f2bf(tile[kkl * 32 + l16 * 8 + j][htl * 16 + l15]);
      size_t off = ((size_t)((e * 32 + dtile * 2 + kkl) * 64 + htile * 4 + htl)) * 512 + lane * 8;
      *reinterpret_cast<u16x8*>(w1t + off) = v;
    }
  } else {
    const int pid = id - 2048;
    const int b = pid >> 3, sb = pid & 7, t = threadIdx.x;
    const int* xr = x + b * S_ + sb * 64;
    float4 acc = make_float4(0.f, 0.f, 0.f, 0.f);
    #pragma unroll 4
    for (int s = 0; s < 64; ++s) {
      const float4* row = reinterpret_cast<const float4*>(emb + (size_t)xr[s] * D_);
      float4 v = row[t];
      acc.x += v.x; acc.y += v.y; acc.z += v.z; acc.w += v.w;
    }
    reinterpret_cast<float4*>(partial + ((size_t)b * 8 + sb) * D_)[t] = acc;
  }
}

// ---------------------------------------------------------------------------
// Kernel 1: reduce partials + gating MLP + top-2 + renormalize (all f32)
__global__ void gate_kernel(const float* __restrict__ partial,
                            const float* __restrict__ gw1, const float* __restrict__ gb1,
                            const float* __restrict__ gw2, const float* __restrict__ gb2,
                            int* __restrict__ ridx, float* __restrict__ rwgt) {
  const int b = blockIdx.x, j = threadIdx.x;
  __shared__ float pl[D_];
  __shared__ float hid[GH_];
  __shared__ float logits[E_];
  for (int d = j; d < D_; d += 256) {
    float s = 0.f;
    #pragma unroll
    for (int sb = 0; sb < 8; ++sb) s += partial[((size_t)b * 8 + sb) * D_ + d];
    pl[d] = s * (1.f / (float)S_);
  }
  __syncthreads();
  float acc = gb1[j];
  for (int d = 0; d < D_; ++d) acc += pl[d] * gw1[d * GH_ + j];
  hid[j] = fmaxf(acc, 0.f);
  __syncthreads();
  if (j < E_) {
    float l = gb2[j];
    for (int i = 0; i < GH_; ++i) l += hid[i] * gw2[i * E_ + j];
    logits[j] = l;
  }
  __syncthreads();
  if (j == 0) {
    int i0 = 0; float v0 = logits[0];
    for (int i = 1; i < E_; ++i) if (logits[i] > v0) { v0 = logits[i]; i0 = i; }
    int i1 = -1; float v1 = -3.0e38f;
    for (int i = 0; i < E_; ++i) {
      if (i == i0) continue;
      if (logits[i] > v1) { v1 = logits[i]; i1 = i; }
    }
    float r1 = expf(v1 - v0);
    float norm = 1.f + r1;
    ridx[b * 2 + 0] = i0;         ridx[b * 2 + 1] = i1;
    rwgt[b * 2 + 0] = 1.f / norm; rwgt[b * 2 + 1] = r1 / norm;
  }
}

// ---------------------------------------------------------------------------
// Kernel 2: stable counting-rank sort of pairs by expert id. 1 block, 128 thr.
__global__ void sort_pairs_kernel(const int* __restrict__ ridx, int* __restrict__ order) {
  __shared__ int se[NPAIR];
  const int t = threadIdx.x;
  se[t] = ridx[t];
  __syncthreads();
  const int e = se[t];
  int rank = 0;
  for (int j = 0; j < NPAIR; ++j) {
    const int ej = se[j];
    rank += (ej < e || (ej == e && j < t)) ? 1 : 0;
  }
  order[rank] = t;
}

// ---------------------------------------------------------------------------
// Kernel 3: token-stationary gathered GEMM + bias + ReLU + sum over s.
//   EXACT round-4 algorithm (best measured), re-partitioned into 16 waves of
//   1024 threads: wave tile 64h x 64s (acc[4][4] = 64 VGPR, total ~120 ->
//   16 waves resident = 4 waves/SIMD, 2x the TLP of the 8-wave version).
//   Block owns 64 tokens x ALL H=1024, K=1024. Token tile (64x1024 bf16,
//   swizzled) in LDS (128 KiB), each slab written once, gather 2 slabs ahead.
//   A (w1t) fragment-direct global->VGPR (L2-resident via sort+XCD chunking).
// grid(1024), block 1024; pairs sorted by expert + XCD-chunked.
__global__ __launch_bounds__(1024) void expert_kernel(
    const int* __restrict__ x, const float* __restrict__ exp_emb,
    const ushort* __restrict__ w1t, const float* __restrict__ exp_b1,
    const int* __restrict__ ridx, const int* __restrict__ order,
    float* __restrict__ p_part) {
  const int id     = blockIdx.x;           // 0..1023
  const int xcd    = id & 7;
  const int within = id >> 3;              // 0..127
  const int slot   = xcd * 128 + within;   // contiguous sorted chunk per XCD
  const int pr     = order[slot >> 3];
  const int sblk   = slot & 7;
  const int b      = pr >> 1;
  const int tid    = threadIdx.x;

  __shared__ __align__(16) ushort lB[64 * 1024];   // 128 KiB token tile

  const int e = ridx[pr];

  // gather mapping: thread covers token row (tid>>4), 4 floats at (tid&15)*4
  const int grow = tid >> 4, kq4 = (tid & 15) * 4;
  const int tok  = x[b * S_ + sblk * 64 + grow];
  const float* gptr = exp_emb + ((size_t)e * V_ + tok) * D_ + kq4;
  const int swz  = (grow & 7) << 3;
  const int gdst = grow * 1024 + (((kq4 & ~7) ^ swz) + (kq4 & 7));  // + slab*64

  const int wid = tid >> 6, lane = tid & 63;
  const int l15 = lane & 15, l16 = lane >> 4;
  const int sw  = (l15 & 7) << 3;

  // A fragment stream: frag(kk, i) at aLane + (kk*64 + wid*4 + i)*512
  const ushort* aLane = w1t + (size_t)e * (32 * 64 * 512)
                        + ((size_t)wid * 4) * 512 + (size_t)lane * 8;
  #define LOADA(kk_, i_) \
    (*reinterpret_cast<const bf16x8*>(aLane + ((size_t)((kk_) * 64 + (i_))) * 512))

  f32x4 acc[4][4];
  #pragma unroll
  for (int i = 0; i < 4; ++i)
    #pragma unroll
    for (int j = 0; j < 4; ++j) acc[i][j] = (f32x4){0.f, 0.f, 0.f, 0.f};

  // ---- prologue: slab0 loaded+written; slab1 loads held in stP[1]
  f32x4 stP[2];
  stP[0] = __builtin_nontemporal_load(reinterpret_cast<const f32x4*>(gptr));
  {
    uint2 w;
    w.x = pk2(stP[0][0], stP[0][1]); w.y = pk2(stP[0][2], stP[0][3]);
    *reinterpret_cast<uint2*>(&lB[gdst]) = w;
  }
  stP[1] = __builtin_nontemporal_load(reinterpret_cast<const f32x4*>(gptr + 64));
  __syncthreads();

  // ---- main loop: 16 slabs; at iter s: lB has slabs [0,s], stP[(s+1)&1] = slab s+1
  #pragma unroll
  for (int s = 0; s < 16; ++s) {
    const int cur = s & 1;
    // (a) issue gather for slab s+2 into stP[cur] (parity (s+2)&1 == cur)
    if (s + 2 < 16) {
      stP[cur] = __builtin_nontemporal_load(
          reinterpret_cast<const f32x4*>(gptr + (s + 2) * 64));
    }
    // (b) compute kk = 2s, 2s+1 on slab s
    #pragma unroll
    for (int ks = 0; ks < 2; ++ks) {
      const int kk = s * 2 + ks;
      const int colk = s * 64 + (((ks << 5) | (l16 << 3)) ^ sw);
      bf16x8 bfr[4], af[4];
      #pragma unroll
      for (int j = 0; j < 4; ++j)
        bfr[j] = *reinterpret_cast<const bf16x8*>(&lB[(j * 16 + l15) * 1024 + colk]);
      #pragma unroll
      for (int i = 0; i < 4; ++i) af[i] = LOADA(kk, i);
      #pragma unroll
      for (int i = 0; i < 4; ++i)
        #pragma unroll
        for (int j = 0; j < 4; ++j)
          acc[i][j] = __builtin_amdgcn_mfma_f32_16x16x32_bf16(af[i], bfr[j], acc[i][j], 0, 0, 0);
    }
    // (c) write slab s+1 from stP[cur^1]
    if (s + 1 < 16) {
      uint2 w;
      w.x = pk2(stP[cur ^ 1][0], stP[cur ^ 1][1]);
      w.y = pk2(stP[cur ^ 1][2], stP[cur ^ 1][3]);
      *reinterpret_cast<uint2*>(&lB[gdst + (s + 1) * 64]) = w;
    }
    __syncthreads();
  }
  #undef LOADA

  // ---- epilogue: + bias, ReLU, sum over 64 s columns, store partials
  float* outRow = p_part + (size_t)(sblk * NPAIR + pr) * H_;
  const float* biasE = exp_b1 + e * H_;
  #pragma unroll
  for (int i = 0; i < 4; ++i) {
    #pragma unroll
    for (int r = 0; r < 4; ++r) {
      const int h = wid * 64 + i * 16 + l16 * 4 + r;
      const float bias = biasE[h];
      float v = 0.f;
      #pragma unroll
      for (int j = 0; j < 4; ++j) v += fmaxf(acc[i][j][r] + bias, 0.f);
      #pragma unroll
      for (int m = 1; m < 16; m <<= 1) v += __shfl_xor(v, m);  // reduce 16 s-cols
      if (l15 == 0) outRow[h] = v;
    }
  }
}

// ---------------------------------------------------------------------------
// Kernel 4: out[b][c] = sum_k rw * ( (sum_sb p_part)/S @ W2[e] + b2[e] )
__global__ void finalize_kernel(const float* __restrict__ p_part,
                                const int* __restrict__ ridx, const float* __restrict__ rwgt,
                                const float* __restrict__ w2, const float* __restrict__ b2,
                                float* __restrict__ out) {
  const int b = blockIdx.x, t = threadIdx.x;
  const int c = t & 15, g = t >> 4;
  __shared__ float red[16][17];
  float res = 0.f;
  for (int kk = 0; kk < 2; ++kk) {
    const int pr = b * 2 + kk;
    const int e = ridx[pr];
    const float w = rwgt[pr];
    float dot = 0.f;
    for (int h = g; h < H_; h += 16) {
      float pm = 0.f;
      #pragma unroll
      for (int sb = 0; sb < 8; ++sb) pm += p_part[(size_t)(sb * NPAIR + pr) * H_ + h];
      dot += pm * w2[((size_t)e * H_ + h) * C_ + c];
    }
    red[g][c] = dot;
    __syncthreads();
    if (g == 0) {
      float s = 0.f;
      #pragma unroll
      for (int i = 0; i < 16; ++i) s += red[i][c];
      res += w * (s * (1.f / (float)S_) + b2[e * C_ + c]);
    }
    __syncthreads();
  }
  if (g == 0) out[b * C_ + c] = res;
}

// ---------------------------------------------------------------------------
extern "C" void kernel_launch(void* const* d_in, const int* in_sizes, int n_in,
                              void* d_out, int out_size, void* d_ws, size_t ws_size,
                              hipStream_t stream) {
  const int*   x    = (const int*)  d_in[0];
  const float* emb  = (const float*)d_in[1];
  const float* gw1  = (const float*)d_in[2];
  const float* gb1  = (const float*)d_in[3];
  const float* gw2  = (const float*)d_in[4];
  const float* gb2  = (const float*)d_in[5];
  const float* eemb = (const float*)d_in[6];
  const float* ew1  = (const float*)d_in[7];
  const float* eb1  = (const float*)d_in[8];
  const float* ew2  = (const float*)d_in[9];
  const float* eb2  = (const float*)d_in[10];
  float* out = (float*)d_out;

  char* ws = (char*)d_ws;
  const size_t OFF_W1T   = 0;                            // 16 MiB
  const size_t OFF_PART  = (size_t)16 << 20;             // 2 MiB
  const size_t OFF_RIDX  = OFF_PART + ((size_t)2 << 20);
  const size_t OFF_RWGT  = OFF_RIDX + 1024;
  const size_t OFF_ORDER = OFF_RWGT + 1024;
  const size_t OFF_PPART = OFF_ORDER + 1024;             // 4 MiB

  ushort* w1t    = (ushort*)(ws + OFF_W1T);
  float*  part   = (float*) (ws + OFF_PART);
  int*    ridx   = (int*)   (ws + OFF_RIDX);
  float*  rwgt   = (float*) (ws + OFF_RWGT);
  int*    order  = (int*)   (ws + OFF_ORDER);
  float*  ppart  = (float*) (ws + OFF_PPART);

  prep_kernel<<<dim3(2560), 256, 0, stream>>>(ew1, w1t, x, emb, part);
  gate_kernel<<<dim3(B_), 256, 0, stream>>>(part, gw1, gb1, gw2, gb2, ridx, rwgt);
  sort_pairs_kernel<<<dim3(1), 128, 0, stream>>>(ridx, order);
  expert_kernel<<<dim3(1024), 1024, 0, stream>>>(x, eemb, w1t, eb1, ridx, order, ppart);
  finalize_kernel<<<dim3(B_), 256, 0, stream>>>(ppart, ridx, rwgt, ew2, eb2, out);
}